// Round 9
// baseline (389.535 us; speedup 1.0000x reference)
//
#include <hip/hip_runtime.h>
#include <hip/hip_bf16.h>

typedef unsigned short u16;
typedef __attribute__((ext_vector_type(8))) short bfrag;   // 8 bf16 = 4 VGPR (MFMA A/B frag)
typedef __attribute__((ext_vector_type(4))) float f32x4;   // MFMA C/D frag
typedef __attribute__((ext_vector_type(8))) unsigned short us8;
typedef __attribute__((ext_vector_type(4))) unsigned short us4;

__device__ __forceinline__ u16 f2bf(float f) {
  union { float f; unsigned int u; } x; x.f = f;
  unsigned int r = x.u + 0x7fffu + ((x.u >> 16) & 1u);
  return (u16)(r >> 16);
}
__device__ __forceinline__ float bf2f(u16 u) {
  union { unsigned int u; float f; } x; x.u = ((unsigned int)u) << 16;
  return x.f;
}

__device__ __forceinline__ void gld16(const void* g, void* l) {
  __builtin_amdgcn_global_load_lds((const __attribute__((address_space(1))) void*)g,
                                   (__attribute__((address_space(3))) void*)l, 16, 0, 0);
}

// ---------------------------------------------------------------------------
// Kernel 0: transpose + convert weights: W[k][n] f32 (1024x1024) -> Wt[n][k] bf16
// ---------------------------------------------------------------------------
__global__ __launch_bounds__(256) void transpose_w(const float* __restrict__ W0,
                                                   const float* __restrict__ W1,
                                                   const float* __restrict__ W2,
                                                   u16* __restrict__ T0,
                                                   u16* __restrict__ T1,
                                                   u16* __restrict__ T2) {
  const float* W = (blockIdx.z == 0) ? W0 : ((blockIdx.z == 1) ? W1 : W2);
  u16* T = (blockIdx.z == 0) ? T0 : ((blockIdx.z == 1) ? T1 : T2);
  __shared__ u16 tile[64][72];
  const int t = threadIdx.x;
  const int rr = t >> 4;
  const int cc = (t & 15) * 4;
  const int kbase = blockIdx.y * 64, nbase = blockIdx.x * 64;
#pragma unroll
  for (int j = 0; j < 4; ++j) {
    int kl = rr + j * 16;
    float4 v = *(const float4*)(W + (size_t)(kbase + kl) * 1024 + nbase + cc);
    tile[kl][cc + 0] = f2bf(v.x);
    tile[kl][cc + 1] = f2bf(v.y);
    tile[kl][cc + 2] = f2bf(v.z);
    tile[kl][cc + 3] = f2bf(v.w);
  }
  __syncthreads();
#pragma unroll
  for (int j = 0; j < 4; ++j) {
    int nl = rr + j * 16;
    us4 o;
    o[0] = tile[cc + 0][nl];
    o[1] = tile[cc + 1][nl];
    o[2] = tile[cc + 2][nl];
    o[3] = tile[cc + 3][nl];
    *(us4*)(T + (size_t)(nbase + nl) * 1024 + kbase + cc) = o;
  }
}

// ---------------------------------------------------------------------------
// Kernel 1: f32 -> bf16 convert (vectorized, grid-stride)
// ---------------------------------------------------------------------------
__global__ __launch_bounds__(256) void cvt_bf16(const float* __restrict__ src,
                                                u16* __restrict__ dst, int n8) {
  int i = blockIdx.x * blockDim.x + threadIdx.x;
  const int stride = gridDim.x * blockDim.x;
  for (; i < n8; i += stride) {
    const float4* p = (const float4*)(src + (size_t)i * 8);
    float4 v0 = p[0], v1 = p[1];
    us8 o;
    o[0] = f2bf(v0.x); o[1] = f2bf(v0.y); o[2] = f2bf(v0.z); o[3] = f2bf(v0.w);
    o[4] = f2bf(v1.x); o[5] = f2bf(v1.y); o[6] = f2bf(v1.z); o[7] = f2bf(v1.w);
    *(us8*)(dst + (size_t)i * 8) = o;
  }
}

// ---------------------------------------------------------------------------
// Kernel 2: 128x128-tile BT GEMM, BK=32, 256 threads (4 waves, 2M x 2N).
//   R6-proven structure for scores/PV: 16 KB single-buffered LDS, plain
//   2-barrier K-loop, 4-8 blocks/CU co-residency provides pipeline overlap
//   (m97/m114 mechanism). XOR-swizzled LDS: conflict-free ds_read_b128 via
//   pre-swizzled global source for global_load_lds. All inputs bf16.
// C = A[M][K](bf16) x B[N][K]^T(bf16).
// OUT: 0 = bf16 + bias | 1 = bf16 * 1/32 | 2 = lvt-transposed + bias | 3 = f32
// Mask-aware: OUT==1 early-exits bcol>=len; OUT==3 truncates K at ceil32(len).
// ---------------------------------------------------------------------------
template <int OUT>
__global__ __launch_bounds__(256, 4) void gemm128(const u16* __restrict__ gA,
                                                  const u16* __restrict__ gB,
                                                  const float* __restrict__ bias,
                                                  void* __restrict__ outp,
                                                  int K, int ldc,
                                                  size_t aStride, size_t bStride,
                                                  size_t cStride,
                                                  const int* __restrict__ seq) {
  __shared__ u16 Ab[4096];   // 128 rows x 32 (8 KB)
  __shared__ u16 Bb[4096];
  const int tid = threadIdx.x;

  const int bx = blockIdx.x, by = blockIdx.y, bz = blockIdx.z;

  const u16* A = gA + (size_t)bz * aStride;
  const u16* B = gB + (size_t)bz * bStride;
  const int brow = by * 128, bcol = bx * 128;

  const int NT = K >> 5;
  int NTe = NT;
  if constexpr (OUT == 1) {
    if (bcol >= seq[bz]) return;   // masked-out score tile: never read downstream
  }
  if constexpr (OUT == 3) {
    const int len = seq[bz];
    const int nt2 = (len + 31) >> 5;  // probs exactly 0 beyond ceil64(len)
    NTe = nt2 < NT ? nt2 : NT;
  }

  const int wv = tid >> 6, l = tid & 63;
  const int wm = wv >> 1, wn = wv & 1;
  const int fr = l & 15, fq = l >> 4;
  // read-side swizzle: physical granule = fq ^ ((row>>1)&3)
  const int goff = (fq ^ ((fr >> 1) & 3)) * 8;

  // staging: unit = 64 rows x 32 cols (4 KB), thread t -> row t>>2, slot t&3
  const int sr = tid >> 2;                         // unit-local row
  const int sg = (tid & 3) ^ ((tid >> 3) & 3);     // logical (global) granule
  const u16* aS = A + (size_t)(brow + sr) * K + sg * 8;
  const u16* bS = B + (size_t)(bcol + sr) * K + sg * 8;
  u16* const dA = Ab + wv * 512;                   // wave-uniform LDS base
  u16* const dB = Bb + wv * 512;

  f32x4 acc[4][4] = {};

  for (int t = 0; t < NTe; ++t) {
    const int k0 = t << 5;
    gld16(aS + k0, dA);
    gld16(aS + k0 + (size_t)64 * K, dA + 2048);
    gld16(bS + k0, dB);
    gld16(bS + k0 + (size_t)64 * K, dB + 2048);
    __syncthreads();   // drains vmcnt + lgkmcnt (compiler-inserted)

    bfrag a[4], b[4];
#pragma unroll
    for (int m = 0; m < 4; ++m)
      a[m] = *(const bfrag*)(Ab + (wm * 64 + m * 16 + fr) * 32 + goff);
#pragma unroll
    for (int n = 0; n < 4; ++n)
      b[n] = *(const bfrag*)(Bb + (wn * 64 + n * 16 + fr) * 32 + goff);
#pragma unroll
    for (int m = 0; m < 4; ++m)
#pragma unroll
      for (int n = 0; n < 4; ++n)
        acc[m][n] = __builtin_amdgcn_mfma_f32_16x16x32_bf16(a[m], b[n], acc[m][n], 0, 0, 0);
    __syncthreads();
  }

  // epilogue
#pragma unroll
  for (int m = 0; m < 4; ++m) {
    const int r0 = brow + wm * 64 + m * 16 + fq * 4;
#pragma unroll
    for (int n = 0; n < 4; ++n) {
      const int c = bcol + wn * 64 + n * 16 + fr;
      f32x4 vv = acc[m][n];
      if constexpr (OUT == 0) {
        float bb = bias[c];
        u16* C = (u16*)outp;
#pragma unroll
        for (int j = 0; j < 4; ++j) C[(size_t)(r0 + j) * ldc + c] = f2bf(vv[j] + bb);
      } else if constexpr (OUT == 1) {
        u16* C = (u16*)outp + (size_t)bz * cStride;
#pragma unroll
        for (int j = 0; j < 4; ++j) C[(size_t)(r0 + j) * ldc + c] = f2bf(vv[j] * 0.03125f);
      } else if constexpr (OUT == 2) {
        float bb = bias[c];
        const int bz2 = r0 >> 11, mm = r0 & 2047;
        us4 o;
#pragma unroll
        for (int j = 0; j < 4; ++j) o[j] = f2bf(vv[j] + bb);
        *(us4*)((u16*)outp + ((size_t)bz2 * 1024 + c) * 2048 + mm) = o;
      } else {
        float* C = (float*)outp + (size_t)bz * cStride;
#pragma unroll
        for (int j = 0; j < 4; ++j) C[(size_t)(r0 + j) * ldc + c] = vv[j];
      }
    }
  }
}

// ---------------------------------------------------------------------------
// Kernel 3: masked softmax over m, in place on probs (bf16). One block per row.
// ---------------------------------------------------------------------------
__global__ __launch_bounds__(256) void softmax_mask(u16* __restrict__ probs,
                                                    const int* __restrict__ seq) {
  const int bid = blockIdx.x;
  const int b = bid >> 11, n = bid & 2047;
  const int len = seq[b];
  const int len64 = (len + 63) & ~63;
  u16* row = probs + ((size_t)b * 2048 + n) * 2048;
  const int t = threadIdx.x;
  const int w = t >> 6, l = t & 63;

  us8 sv = {};
  if (t * 8 < len) sv = *(const us8*)(row + t * 8);
  float vals[8];
  float vmax = -1e30f;
#pragma unroll
  for (int e = 0; e < 8; ++e) {
    int m = t * 8 + e;
    float x = bf2f(sv[e]);
    vals[e] = (m < len) ? x : -1e30f;
    vmax = fmaxf(vmax, vals[e]);
  }
#pragma unroll
  for (int o = 32; o > 0; o >>= 1) vmax = fmaxf(vmax, __shfl_xor(vmax, o, 64));
  __shared__ float sm[4], ss[4];
  if (l == 0) sm[w] = vmax;
  __syncthreads();
  vmax = fmaxf(fmaxf(sm[0], sm[1]), fmaxf(sm[2], sm[3]));

  float ev[8];
  float sum = 0.f;
#pragma unroll
  for (int e = 0; e < 8; ++e) {
    int m = t * 8 + e;
    float p = (m < len) ? __expf(vals[e] - vmax) : 0.f;
    ev[e] = p;
    sum += p;
  }
#pragma unroll
  for (int o = 32; o > 0; o >>= 1) sum += __shfl_xor(sum, o, 64);
  if (l == 0) ss[w] = sum;
  __syncthreads();
  sum = ss[0] + ss[1] + ss[2] + ss[3];
  float inv = 1.f / sum;
  if (t * 8 < len64) {
    us8 ov;
#pragma unroll
    for (int e = 0; e < 8; ++e) ov[e] = f2bf(ev[e] * inv);
    *(us8*)(row + t * 8) = ov;
  }
}

// ---------------------------------------------------------------------------
extern "C" void kernel_launch(void* const* d_in, const int* in_sizes, int n_in,
                              void* d_out, int out_size, void* d_ws, size_t ws_size,
                              hipStream_t stream) {
  const float* q   = (const float*)d_in[0];
  const float* k   = (const float*)d_in[1];
  const float* v   = (const float*)d_in[2];
  const int*   seq = (const int*)d_in[3];
  const float* Wq  = (const float*)d_in[4];
  const float* bq  = (const float*)d_in[5];
  const float* Wk  = (const float*)d_in[6];
  const float* bk  = (const float*)d_in[7];
  const float* Wv  = (const float*)d_in[8];
  const float* bv  = (const float*)d_in[9];
  float* out = (float*)d_out;

  // workspace layout (u16 elements) — ~166 MB:
  //   wt: 3 x 1M | lq/lk/lvt: 3 x 16M | probs: 33.5M (cvt buffer aliased in)
  u16* ws = (u16*)d_ws;
  u16* wtq = ws;
  u16* wtk = wtq + (size_t)1024 * 1024;
  u16* wtv = wtk + (size_t)1024 * 1024;
  u16* lq  = wtv + (size_t)1024 * 1024;
  u16* lk  = lq + (size_t)16384 * 1024;
  u16* lvt = lk + (size_t)16384 * 1024;
  u16* probs = lvt + (size_t)16384 * 1024;
  u16* cbuf = probs;   // 16M u16 convert buffer, dead before scores GEMM

  const size_t S21 = (size_t)2048 * 1024;   // per-batch stride, 2048x1024
  const size_t S22 = (size_t)2048 * 2048;   // per-batch stride, 2048x2048

  transpose_w<<<dim3(16, 16, 3), 256, 0, stream>>>(Wq, Wk, Wv, wtq, wtk, wtv);

  // Q projection
  cvt_bf16<<<dim3(2048), 256, 0, stream>>>(q, cbuf, 2097152);
  gemm128<0><<<dim3(8, 128), 256, 0, stream>>>(cbuf, wtq, bq, lq, 1024, 1024, 0, 0, 0, nullptr);
  // K projection
  cvt_bf16<<<dim3(2048), 256, 0, stream>>>(k, cbuf, 2097152);
  gemm128<0><<<dim3(8, 128), 256, 0, stream>>>(cbuf, wtk, bk, lk, 1024, 1024, 0, 0, 0, nullptr);
  // V projection -> transposed lvt[b][o][m]
  cvt_bf16<<<dim3(2048), 256, 0, stream>>>(v, cbuf, 2097152);
  gemm128<2><<<dim3(8, 128), 256, 0, stream>>>(cbuf, wtv, bv, lvt, 1024, 1024, 0, 0, 0, nullptr);

  // scores = lq @ lk^T / 32  (per batch, masked tiles skipped)
  gemm128<1><<<dim3(16, 16, 8), 256, 0, stream>>>(lq, lk, nullptr, probs, 1024, 2048, S21, S21, S22, seq);
  // masked softmax in place
  softmax_mask<<<dim3(16384), 256, 0, stream>>>(probs, seq);
  // out = probs @ lv  (per batch, lvt is B^T layout, K truncated at ceil32(len))
  gemm128<3><<<dim3(8, 16, 8), 256, 0, stream>>>(probs, lvt, nullptr, out, 2048, 1024, S22, S21, S21, seq);
}

// Round 10
// 351.668 us; speedup vs baseline: 1.1077x; 1.1077x over previous
//
#include <hip/hip_runtime.h>
#include <hip/hip_bf16.h>

typedef unsigned short u16;
typedef __attribute__((ext_vector_type(8))) short bfrag;   // 8 bf16 = 4 VGPR (MFMA A/B frag)
typedef __attribute__((ext_vector_type(4))) float f32x4;   // MFMA C/D frag
typedef __attribute__((ext_vector_type(8))) unsigned short us8;
typedef __attribute__((ext_vector_type(4))) unsigned short us4;

__device__ __forceinline__ u16 f2bf(float f) {
  union { float f; unsigned int u; } x; x.f = f;
  unsigned int r = x.u + 0x7fffu + ((x.u >> 16) & 1u);
  return (u16)(r >> 16);
}
__device__ __forceinline__ float bf2f(u16 u) {
  union { unsigned int u; float f; } x; x.u = ((unsigned int)u) << 16;
  return x.f;
}

__device__ __forceinline__ void gld16(const void* g, void* l) {
  __builtin_amdgcn_global_load_lds((const __attribute__((address_space(1))) void*)g,
                                   (__attribute__((address_space(3))) void*)l, 16, 0, 0);
}

// ---------------------------------------------------------------------------
// Kernel 0: transpose + convert weights: W[k][n] f32 (1024x1024) -> Wt[n][k] bf16
// ---------------------------------------------------------------------------
__global__ __launch_bounds__(256) void transpose_w(const float* __restrict__ W0,
                                                   const float* __restrict__ W1,
                                                   const float* __restrict__ W2,
                                                   u16* __restrict__ T0,
                                                   u16* __restrict__ T1,
                                                   u16* __restrict__ T2) {
  const float* W = (blockIdx.z == 0) ? W0 : ((blockIdx.z == 1) ? W1 : W2);
  u16* T = (blockIdx.z == 0) ? T0 : ((blockIdx.z == 1) ? T1 : T2);
  __shared__ u16 tile[64][72];
  const int t = threadIdx.x;
  const int rr = t >> 4;
  const int cc = (t & 15) * 4;
  const int kbase = blockIdx.y * 64, nbase = blockIdx.x * 64;
#pragma unroll
  for (int j = 0; j < 4; ++j) {
    int kl = rr + j * 16;
    float4 v = *(const float4*)(W + (size_t)(kbase + kl) * 1024 + nbase + cc);
    tile[kl][cc + 0] = f2bf(v.x);
    tile[kl][cc + 1] = f2bf(v.y);
    tile[kl][cc + 2] = f2bf(v.z);
    tile[kl][cc + 3] = f2bf(v.w);
  }
  __syncthreads();
#pragma unroll
  for (int j = 0; j < 4; ++j) {
    int nl = rr + j * 16;
    us4 o;
    o[0] = tile[cc + 0][nl];
    o[1] = tile[cc + 1][nl];
    o[2] = tile[cc + 2][nl];
    o[3] = tile[cc + 3][nl];
    *(us4*)(T + (size_t)(nbase + nl) * 1024 + kbase + cc) = o;
  }
}

// ---------------------------------------------------------------------------
// Kernel 1: f32 -> bf16 convert (vectorized, grid-stride)
// ---------------------------------------------------------------------------
__global__ __launch_bounds__(256) void cvt_bf16(const float* __restrict__ src,
                                                u16* __restrict__ dst, int n8) {
  int i = blockIdx.x * blockDim.x + threadIdx.x;
  const int stride = gridDim.x * blockDim.x;
  for (; i < n8; i += stride) {
    const float4* p = (const float4*)(src + (size_t)i * 8);
    float4 v0 = p[0], v1 = p[1];
    us8 o;
    o[0] = f2bf(v0.x); o[1] = f2bf(v0.y); o[2] = f2bf(v0.z); o[3] = f2bf(v0.w);
    o[4] = f2bf(v1.x); o[5] = f2bf(v1.y); o[6] = f2bf(v1.z); o[7] = f2bf(v1.w);
    *(us8*)(dst + (size_t)i * 8) = o;
  }
}

// ---------------------------------------------------------------------------
// Kernel 2 (projections): 256x256-tile BT GEMM, BK=64, 512 threads (8 waves),
//   8-phase counted-vmcnt, T2 swizzle, T5 setprio, panel-sharing mapping.
//   (R5/R7-proven ~34 us; B = 2 MB L2-resident weight.)
// OUT: 0 = bf16 + bias | 2 = lvt-transposed + bias
// ---------------------------------------------------------------------------
template <int OUT>
__global__ __launch_bounds__(512, 2) void gemm256(const u16* __restrict__ gA,
                                                  const u16* __restrict__ gB,
                                                  const float* __restrict__ bias,
                                                  void* __restrict__ outp,
                                                  int K, int ldc) {
  __shared__ u16 lds[65536];
  const int tid = threadIdx.x;

  const int id = blockIdx.x + gridDim.x * blockIdx.y;
  const int bx = (id >> 3) & 3, by = (id & 7) + 8 * (id >> 5);

  const u16* A = gA;
  const u16* B = gB;
  const int brow = by * 256, bcol = bx * 256;

  const int wv = tid >> 6, l = tid & 63;
  const int wm = wv >> 2, wn = wv & 3;
  const int fr = l & 15, fq = l >> 4;
  const int g0 = (fq ^ (fr & 7)) * 8;
  const int g1 = ((4 + fq) ^ (fr & 7)) * 8;

  const int srow = tid >> 3;
  const int sg = (tid & 7) ^ (srow & 7);
  const u16* aS = A + (size_t)(brow + srow) * K + sg * 8;
  const u16* bS = B + (size_t)(bcol + srow) * K + sg * 8;
  u16* const dA = lds + wv * 512;
  u16* const dB = lds + 32768 + wv * 512;

  f32x4 acc[8][4] = {};
  const int NT = K >> 6;

  auto stA = [&](int tile, int c, int buf) {
    gld16(aS + (size_t)tile * 64 + (size_t)c * 64 * K, dA + buf * 16384 + c * 4096);
  };
  auto stB = [&](int tile, int c, int buf) {
    gld16(bS + (size_t)tile * 64 + (size_t)c * 64 * K, dB + buf * 16384 + c * 4096);
  };

#pragma unroll
  for (int c = 0; c < 4; ++c) stA(0, c, 0);
#pragma unroll
  for (int c = 0; c < 4; ++c) stB(0, c, 0);
  if (NT > 1) {
    stA(1, 0, 1); stA(1, 2, 1);
    stB(1, 0, 1); stB(1, 1, 1); stB(1, 2, 1); stB(1, 3, 1);
  }

  for (int t = 0; t < NT; ++t) {
    const int cur = t & 1;
    const u16* At = lds + cur * 16384;
    const u16* Bt = lds + 32768 + cur * 16384;

    if (t + 1 < NT) asm volatile("s_waitcnt vmcnt(6)" ::: "memory");
    else            asm volatile("s_waitcnt vmcnt(0)" ::: "memory");
    __builtin_amdgcn_s_barrier();

    bfrag a[4][2], b[2][2][2];

#pragma unroll
    for (int m = 0; m < 4; ++m) {
      const u16* p = At + (wm * 128 + m * 16 + fr) * 64;
      a[m][0] = *(const bfrag*)(p + g0);
      a[m][1] = *(const bfrag*)(p + g1);
    }
#pragma unroll
    for (int n = 0; n < 2; ++n) {
      const u16* p = Bt + (wn * 64 + n * 16 + fr) * 64;
      b[0][n][0] = *(const bfrag*)(p + g0);
      b[0][n][1] = *(const bfrag*)(p + g1);
    }
    if (t + 1 < NT) { stA(t + 1, 1, cur ^ 1); stA(t + 1, 3, cur ^ 1); }
    __builtin_amdgcn_s_barrier();
    asm volatile("s_waitcnt lgkmcnt(0)" ::: "memory");
    __builtin_amdgcn_sched_barrier(0);
    __builtin_amdgcn_s_setprio(1);
#pragma unroll
    for (int n = 0; n < 2; ++n)
#pragma unroll
      for (int m = 0; m < 4; ++m) {
        acc[m][n] = __builtin_amdgcn_mfma_f32_16x16x32_bf16(a[m][0], b[0][n][0], acc[m][n], 0, 0, 0);
        acc[m][n] = __builtin_amdgcn_mfma_f32_16x16x32_bf16(a[m][1], b[0][n][1], acc[m][n], 0, 0, 0);
      }
    __builtin_amdgcn_s_setprio(0);
    __builtin_amdgcn_s_barrier();

#pragma unroll
    for (int n = 0; n < 2; ++n) {
      const u16* p = Bt + (wn * 64 + 32 + n * 16 + fr) * 64;
      b[1][n][0] = *(const bfrag*)(p + g0);
      b[1][n][1] = *(const bfrag*)(p + g1);
    }
    if (t + 2 < NT) { stA(t + 2, 0, cur); stA(t + 2, 2, cur); }
    __builtin_amdgcn_s_barrier();
    asm volatile("s_waitcnt lgkmcnt(0)" ::: "memory");
    __builtin_amdgcn_sched_barrier(0);
    __builtin_amdgcn_s_setprio(1);
#pragma unroll
    for (int n = 0; n < 2; ++n)
#pragma unroll
      for (int m = 0; m < 4; ++m) {
        acc[m][2 + n] = __builtin_amdgcn_mfma_f32_16x16x32_bf16(a[m][0], b[1][n][0], acc[m][2 + n], 0, 0, 0);
        acc[m][2 + n] = __builtin_amdgcn_mfma_f32_16x16x32_bf16(a[m][1], b[1][n][1], acc[m][2 + n], 0, 0, 0);
      }
    __builtin_amdgcn_s_setprio(0);
    __builtin_amdgcn_s_barrier();

#pragma unroll
    for (int m = 0; m < 4; ++m) {
      const u16* p = At + (wm * 128 + 64 + m * 16 + fr) * 64;
      a[m][0] = *(const bfrag*)(p + g0);
      a[m][1] = *(const bfrag*)(p + g1);
    }
    if (t + 2 < NT) { stB(t + 2, 0, cur); stB(t + 2, 1, cur); }
    __builtin_amdgcn_s_barrier();
    asm volatile("s_waitcnt lgkmcnt(0)" ::: "memory");
    __builtin_amdgcn_sched_barrier(0);
    __builtin_amdgcn_s_setprio(1);
#pragma unroll
    for (int n = 0; n < 2; ++n)
#pragma unroll
      for (int m = 0; m < 4; ++m) {
        acc[4 + m][n] = __builtin_amdgcn_mfma_f32_16x16x32_bf16(a[m][0], b[0][n][0], acc[4 + m][n], 0, 0, 0);
        acc[4 + m][n] = __builtin_amdgcn_mfma_f32_16x16x32_bf16(a[m][1], b[0][n][1], acc[4 + m][n], 0, 0, 0);
      }
    __builtin_amdgcn_s_setprio(0);
    __builtin_amdgcn_s_barrier();

    if (t + 2 < NT) { stB(t + 2, 2, cur); stB(t + 2, 3, cur); }
    __builtin_amdgcn_s_setprio(1);
#pragma unroll
    for (int n = 0; n < 2; ++n)
#pragma unroll
      for (int m = 0; m < 4; ++m) {
        acc[4 + m][2 + n] = __builtin_amdgcn_mfma_f32_16x16x32_bf16(a[m][0], b[1][n][0], acc[4 + m][2 + n], 0, 0, 0);
        acc[4 + m][2 + n] = __builtin_amdgcn_mfma_f32_16x16x32_bf16(a[m][1], b[1][n][1], acc[4 + m][2 + n], 0, 0, 0);
      }
    __builtin_amdgcn_s_setprio(0);
    __builtin_amdgcn_s_barrier();
  }

#pragma unroll
  for (int mg = 0; mg < 8; ++mg) {
    const int r0 = brow + wm * 128 + mg * 16 + fq * 4;
#pragma unroll
    for (int n = 0; n < 4; ++n) {
      const int c = bcol + wn * 64 + n * 16 + fr;
      f32x4 vv = acc[mg][n];
      float bb = bias[c];
      if constexpr (OUT == 0) {
        u16* C = (u16*)outp;
#pragma unroll
        for (int j = 0; j < 4; ++j) C[(size_t)(r0 + j) * ldc + c] = f2bf(vv[j] + bb);
      } else {
        const int bz2 = r0 >> 11, mm = r0 & 2047;
        us4 o;
#pragma unroll
        for (int j = 0; j < 4; ++j) o[j] = f2bf(vv[j] + bb);
        *(us4*)((u16*)outp + ((size_t)bz2 * 1024 + c) * 2048 + mm) = o;
      }
    }
  }
}

// ---------------------------------------------------------------------------
// Kernel 3 (scores/PV): 128x128-tile BT GEMM, BK=64, 512 threads (8 waves,
//   2M x 4N). 64 KiB LDS double-buffered -> 2 blocks/CU (R7: scores 76.6 us).
// OUT==1 (scores): early-exit masked cols; z = batch.
// OUT==3 (PV): selective split-K. z = (half<<3)|batch. h0 computes tiles
//   [0,min(NTe,16)) -> out; h1 computes [16,NTe) (exit if NTe<=16) -> p1.
//   Chain wall drops 32 -> 16 tiles for the guaranteed len=2048 batch.
// ---------------------------------------------------------------------------
template <int OUT>
__global__ __launch_bounds__(512, 4) void gemm128d(const u16* __restrict__ gA,
                                                   const u16* __restrict__ gB,
                                                   void* __restrict__ outp,
                                                   int K, int ldc,
                                                   size_t aStride, size_t bStride,
                                                   size_t cStride,
                                                   const int* __restrict__ seq,
                                                   float* __restrict__ p1) {
  __shared__ u16 lds[32768];   // A: 2 bufs of 8192 u16; B: +16384
  const int tid = threadIdx.x;
  const int bx = blockIdx.x, by = blockIdx.y;

  int bz, half = 0;
  if constexpr (OUT == 3) { bz = blockIdx.z & 7; half = blockIdx.z >> 3; }
  else bz = blockIdx.z;

  const u16* A = gA + (size_t)bz * aStride;
  const u16* B = gB + (size_t)bz * bStride;
  const int brow = by * 128, bcol = bx * 128;

  const int NT = K >> 6;
  int t0 = 0, t1 = NT;
  if constexpr (OUT == 1) {
    if (bcol >= seq[bz]) return;
  }
  if constexpr (OUT == 3) {
    int nt2 = (seq[bz] + 63) >> 6;
    nt2 = nt2 < NT ? nt2 : NT;
    if (half == 0) { t0 = 0; t1 = nt2 < 16 ? nt2 : 16; }
    else           { if (nt2 <= 16) return; t0 = 16; t1 = nt2; }
  }

  const int wv = tid >> 6, l = tid & 63;
  const int wm = wv >> 2, wn = wv & 3;          // 2M x 4N
  const int fr = l & 15, fq = l >> 4;
  const int g0 = (fq ^ (fr & 7)) * 8;
  const int g1 = ((4 + fq) ^ (fr & 7)) * 8;

  const int srow = tid >> 3;                    // 0..63
  const int sg = (tid & 7) ^ (srow & 7);
  const u16* aS = A + (size_t)(brow + srow) * K + sg * 8;
  const u16* bS = B + (size_t)(bcol + srow) * K + sg * 8;
  u16* const dA = lds + wv * 512;
  u16* const dB = lds + 16384 + wv * 512;

  f32x4 acc[4][2] = {};

  auto stage = [&](int tile, int buf) {
#pragma unroll
    for (int c = 0; c < 2; ++c)
      gld16(aS + (size_t)tile * 64 + (size_t)c * 64 * K, dA + buf * 8192 + c * 4096);
#pragma unroll
    for (int c = 0; c < 2; ++c)
      gld16(bS + (size_t)tile * 64 + (size_t)c * 64 * K, dB + buf * 8192 + c * 4096);
  };

  // prologue
  stage(t0, t0 & 1);
  asm volatile("s_waitcnt vmcnt(0)" ::: "memory");
  __builtin_amdgcn_s_barrier();

  for (int t = t0; t < t1; ++t) {
    const int cur = t & 1;
    const u16* At = lds + cur * 8192;
    const u16* Bt = lds + 16384 + cur * 8192;

    if (t + 1 < t1) stage(t + 1, cur ^ 1);   // issue early; lands during MFMA

    bfrag a[4][2], b[2][2];
#pragma unroll
    for (int m = 0; m < 4; ++m) {
      const u16* p = At + (wm * 64 + m * 16 + fr) * 64;
      a[m][0] = *(const bfrag*)(p + g0);
      a[m][1] = *(const bfrag*)(p + g1);
    }
#pragma unroll
    for (int n = 0; n < 2; ++n) {
      const u16* p = Bt + (wn * 32 + n * 16 + fr) * 64;
      b[n][0] = *(const bfrag*)(p + g0);
      b[n][1] = *(const bfrag*)(p + g1);
    }
    asm volatile("s_waitcnt lgkmcnt(0)" ::: "memory");
    __builtin_amdgcn_sched_barrier(0);
    __builtin_amdgcn_s_setprio(1);
#pragma unroll
    for (int m = 0; m < 4; ++m)
#pragma unroll
      for (int n = 0; n < 2; ++n) {
        acc[m][n] = __builtin_amdgcn_mfma_f32_16x16x32_bf16(a[m][0], b[n][0], acc[m][n], 0, 0, 0);
        acc[m][n] = __builtin_amdgcn_mfma_f32_16x16x32_bf16(a[m][1], b[n][1], acc[m][n], 0, 0, 0);
      }
    __builtin_amdgcn_s_setprio(0);
    if (t + 1 < t1) asm volatile("s_waitcnt vmcnt(0)" ::: "memory");
    __builtin_amdgcn_s_barrier();
  }

  // epilogue
#pragma unroll
  for (int m = 0; m < 4; ++m) {
    const int r0 = brow + wm * 64 + m * 16 + fq * 4;
#pragma unroll
    for (int n = 0; n < 2; ++n) {
      const int c = bcol + wn * 32 + n * 16 + fr;
      f32x4 vv = acc[m][n];
      if constexpr (OUT == 1) {
        u16* C = (u16*)outp + (size_t)bz * cStride;
#pragma unroll
        for (int j = 0; j < 4; ++j) C[(size_t)(r0 + j) * ldc + c] = f2bf(vv[j] * 0.03125f);
      } else {
        float* C = (half ? p1 : (float*)outp) + (size_t)bz * cStride;
#pragma unroll
        for (int j = 0; j < 4; ++j) C[(size_t)(r0 + j) * ldc + c] = vv[j];
      }
    }
  }
}

// ---------------------------------------------------------------------------
// Kernel 4: out[b] += p1[b] for split batches (len > 1024). float4 per thread.
// ---------------------------------------------------------------------------
__global__ __launch_bounds__(256) void reduce_add(float* __restrict__ out,
                                                  const float* __restrict__ p1,
                                                  const int* __restrict__ seq) {
  const int b = blockIdx.z;
  if (seq[b] <= 1024) return;
  const size_t base = (size_t)b * 2048 * 1024 + ((size_t)blockIdx.x * 256 + threadIdx.x) * 4;
  float4 a = *(const float4*)(out + base);
  float4 c = *(const float4*)(p1 + base);
  a.x += c.x; a.y += c.y; a.z += c.z; a.w += c.w;
  *(float4*)(out + base) = a;
}

// ---------------------------------------------------------------------------
// Kernel 5: masked softmax over m, in place on probs (bf16). One block per row.
// ---------------------------------------------------------------------------
__global__ __launch_bounds__(256) void softmax_mask(u16* __restrict__ probs,
                                                    const int* __restrict__ seq) {
  const int bid = blockIdx.x;
  const int b = bid >> 11, n = bid & 2047;
  const int len = seq[b];
  const int len64 = (len + 63) & ~63;
  u16* row = probs + ((size_t)b * 2048 + n) * 2048;
  const int t = threadIdx.x;
  const int w = t >> 6, l = t & 63;

  us8 sv = {};
  if (t * 8 < len) sv = *(const us8*)(row + t * 8);
  float vals[8];
  float vmax = -1e30f;
#pragma unroll
  for (int e = 0; e < 8; ++e) {
    int m = t * 8 + e;
    float x = bf2f(sv[e]);
    vals[e] = (m < len) ? x : -1e30f;
    vmax = fmaxf(vmax, vals[e]);
  }
#pragma unroll
  for (int o = 32; o > 0; o >>= 1) vmax = fmaxf(vmax, __shfl_xor(vmax, o, 64));
  __shared__ float sm[4], ss[4];
  if (l == 0) sm[w] = vmax;
  __syncthreads();
  vmax = fmaxf(fmaxf(sm[0], sm[1]), fmaxf(sm[2], sm[3]));

  float ev[8];
  float sum = 0.f;
#pragma unroll
  for (int e = 0; e < 8; ++e) {
    int m = t * 8 + e;
    float p = (m < len) ? __expf(vals[e] - vmax) : 0.f;
    ev[e] = p;
    sum += p;
  }
#pragma unroll
  for (int o = 32; o > 0; o >>= 1) sum += __shfl_xor(sum, o, 64);
  if (l == 0) ss[w] = sum;
  __syncthreads();
  sum = ss[0] + ss[1] + ss[2] + ss[3];
  float inv = 1.f / sum;
  if (t * 8 < len64) {
    us8 ov;
#pragma unroll
    for (int e = 0; e < 8; ++e) ov[e] = f2bf(ev[e] * inv);
    *(us8*)(row + t * 8) = ov;
  }
}

// ---------------------------------------------------------------------------
extern "C" void kernel_launch(void* const* d_in, const int* in_sizes, int n_in,
                              void* d_out, int out_size, void* d_ws, size_t ws_size,
                              hipStream_t stream) {
  const float* q   = (const float*)d_in[0];
  const float* k   = (const float*)d_in[1];
  const float* v   = (const float*)d_in[2];
  const int*   seq = (const int*)d_in[3];
  const float* Wq  = (const float*)d_in[4];
  const float* bq  = (const float*)d_in[5];
  const float* Wk  = (const float*)d_in[6];
  const float* bk  = (const float*)d_in[7];
  const float* Wv  = (const float*)d_in[8];
  const float* bv  = (const float*)d_in[9];
  float* out = (float*)d_out;

  // workspace layout (u16 elements) — ~174 MB:
  //   wt: 3 x 1M | lq/lk/lvt: 3 x 16M | probs: 33.5M
  //   cvt buffer aliases probs (dead before scores); PV split partials
  //   alias lq+lk (dead after scores): 16.8M f32 = 67 MB.
  u16* ws = (u16*)d_ws;
  u16* wtq = ws;
  u16* wtk = wtq + (size_t)1024 * 1024;
  u16* wtv = wtk + (size_t)1024 * 1024;
  u16* lq  = wtv + (size_t)1024 * 1024;
  u16* lk  = lq + (size_t)16384 * 1024;
  u16* lvt = lk + (size_t)16384 * 1024;
  u16* probs = lvt + (size_t)16384 * 1024;
  u16* cbuf = probs;          // 16M u16 convert buffer
  float* p1 = (float*)lq;     // 16.8M f32 PV partials (aliases lq+lk)

  const size_t S21 = (size_t)2048 * 1024;   // per-batch stride, 2048x1024
  const size_t S22 = (size_t)2048 * 2048;   // per-batch stride, 2048x2048

  transpose_w<<<dim3(16, 16, 3), 256, 0, stream>>>(Wq, Wk, Wv, wtq, wtk, wtv);

  // Q projection
  cvt_bf16<<<dim3(2048), 256, 0, stream>>>(q, cbuf, 2097152);
  gemm256<0><<<dim3(4, 64, 1), 512, 0, stream>>>(cbuf, wtq, bq, lq, 1024, 1024);
  // K projection
  cvt_bf16<<<dim3(2048), 256, 0, stream>>>(k, cbuf, 2097152);
  gemm256<0><<<dim3(4, 64, 1), 512, 0, stream>>>(cbuf, wtk, bk, lk, 1024, 1024);
  // V projection -> transposed lvt[b][o][m]
  cvt_bf16<<<dim3(2048), 256, 0, stream>>>(v, cbuf, 2097152);
  gemm256<2><<<dim3(4, 64, 1), 512, 0, stream>>>(cbuf, wtv, bv, lvt, 1024, 1024);

  // scores = lq @ lk^T / 32  (per batch, masked tiles skipped)
  gemm128d<1><<<dim3(16, 16, 8), 512, 0, stream>>>(lq, lk, probs, 1024, 2048,
                                                   S21, S21, S22, seq, nullptr);
  // masked softmax in place
  softmax_mask<<<dim3(16384), 256, 0, stream>>>(probs, seq);
  // out = probs @ lv  (split-K: z = (half<<3)|batch; h1 -> p1 for len>1024)
  gemm128d<3><<<dim3(8, 16, 16), 512, 0, stream>>>(probs, lvt, out, 2048, 1024,
                                                   S22, S21, S21, seq, p1);
  // out[b] += p1[b] for split batches
  reduce_add<<<dim3(2048, 1, 8), 256, 0, stream>>>(out, p1, seq);
}

// Round 11
// 321.457 us; speedup vs baseline: 1.2118x; 1.0940x over previous
//
#include <hip/hip_runtime.h>
#include <hip/hip_bf16.h>

typedef unsigned short u16;
typedef __attribute__((ext_vector_type(8))) short bfrag;   // 8 bf16 = 4 VGPR (MFMA A/B frag)
typedef __attribute__((ext_vector_type(4))) float f32x4;   // MFMA C/D frag
typedef __attribute__((ext_vector_type(8))) unsigned short us8;
typedef __attribute__((ext_vector_type(4))) unsigned short us4;

__device__ __forceinline__ u16 f2bf(float f) {
  union { float f; unsigned int u; } x; x.f = f;
  unsigned int r = x.u + 0x7fffu + ((x.u >> 16) & 1u);
  return (u16)(r >> 16);
}
__device__ __forceinline__ float bf2f(u16 u) {
  union { unsigned int u; float f; } x; x.u = ((unsigned int)u) << 16;
  return x.f;
}

__device__ __forceinline__ void gld16(const void* g, void* l) {
  __builtin_amdgcn_global_load_lds((const __attribute__((address_space(1))) void*)g,
                                   (__attribute__((address_space(3))) void*)l, 16, 0, 0);
}

// ---------------------------------------------------------------------------
// Kernel 0: transpose + convert weights: W[k][n] f32 (1024x1024) -> Wt[n][k] bf16
// ---------------------------------------------------------------------------
__global__ __launch_bounds__(256) void transpose_w(const float* __restrict__ W0,
                                                   const float* __restrict__ W1,
                                                   const float* __restrict__ W2,
                                                   u16* __restrict__ T0,
                                                   u16* __restrict__ T1,
                                                   u16* __restrict__ T2) {
  const float* W = (blockIdx.z == 0) ? W0 : ((blockIdx.z == 1) ? W1 : W2);
  u16* T = (blockIdx.z == 0) ? T0 : ((blockIdx.z == 1) ? T1 : T2);
  __shared__ u16 tile[64][72];
  const int t = threadIdx.x;
  const int rr = t >> 4;
  const int cc = (t & 15) * 4;
  const int kbase = blockIdx.y * 64, nbase = blockIdx.x * 64;
#pragma unroll
  for (int j = 0; j < 4; ++j) {
    int kl = rr + j * 16;
    float4 v = *(const float4*)(W + (size_t)(kbase + kl) * 1024 + nbase + cc);
    tile[kl][cc + 0] = f2bf(v.x);
    tile[kl][cc + 1] = f2bf(v.y);
    tile[kl][cc + 2] = f2bf(v.z);
    tile[kl][cc + 3] = f2bf(v.w);
  }
  __syncthreads();
#pragma unroll
  for (int j = 0; j < 4; ++j) {
    int nl = rr + j * 16;
    us4 o;
    o[0] = tile[cc + 0][nl];
    o[1] = tile[cc + 1][nl];
    o[2] = tile[cc + 2][nl];
    o[3] = tile[cc + 3][nl];
    *(us4*)(T + (size_t)(nbase + nl) * 1024 + kbase + cc) = o;
  }
}

// ---------------------------------------------------------------------------
// Kernel 1: f32 -> bf16 convert (vectorized, grid-stride)
// ---------------------------------------------------------------------------
__global__ __launch_bounds__(256) void cvt_bf16(const float* __restrict__ src,
                                                u16* __restrict__ dst, int n8) {
  int i = blockIdx.x * blockDim.x + threadIdx.x;
  const int stride = gridDim.x * blockDim.x;
  for (; i < n8; i += stride) {
    const float4* p = (const float4*)(src + (size_t)i * 8);
    float4 v0 = p[0], v1 = p[1];
    us8 o;
    o[0] = f2bf(v0.x); o[1] = f2bf(v0.y); o[2] = f2bf(v0.z); o[3] = f2bf(v0.w);
    o[4] = f2bf(v1.x); o[5] = f2bf(v1.y); o[6] = f2bf(v1.z); o[7] = f2bf(v1.w);
    *(us8*)(dst + (size_t)i * 8) = o;
  }
}

// ---------------------------------------------------------------------------
// Kernel 2 (projections): 256x256-tile BT GEMM, BK=64, 512 threads (8 waves),
//   8-phase counted-vmcnt, T2 swizzle, T5 setprio, panel-sharing mapping.
//   (R5/R10-proven ~34 us; B = 2 MB L2-resident weight.)
// OUT: 0 = bf16 + bias | 2 = lvt-transposed + bias
// ---------------------------------------------------------------------------
template <int OUT>
__global__ __launch_bounds__(512, 2) void gemm256(const u16* __restrict__ gA,
                                                  const u16* __restrict__ gB,
                                                  const float* __restrict__ bias,
                                                  void* __restrict__ outp,
                                                  int K, int ldc) {
  __shared__ u16 lds[65536];
  const int tid = threadIdx.x;

  const int id = blockIdx.x + gridDim.x * blockIdx.y;
  const int bx = (id >> 3) & 3, by = (id & 7) + 8 * (id >> 5);

  const u16* A = gA;
  const u16* B = gB;
  const int brow = by * 256, bcol = bx * 256;

  const int wv = tid >> 6, l = tid & 63;
  const int wm = wv >> 2, wn = wv & 3;
  const int fr = l & 15, fq = l >> 4;
  const int g0 = (fq ^ (fr & 7)) * 8;
  const int g1 = ((4 + fq) ^ (fr & 7)) * 8;

  const int srow = tid >> 3;
  const int sg = (tid & 7) ^ (srow & 7);
  const u16* aS = A + (size_t)(brow + srow) * K + sg * 8;
  const u16* bS = B + (size_t)(bcol + srow) * K + sg * 8;
  u16* const dA = lds + wv * 512;
  u16* const dB = lds + 32768 + wv * 512;

  f32x4 acc[8][4] = {};
  const int NT = K >> 6;

  auto stA = [&](int tile, int c, int buf) {
    gld16(aS + (size_t)tile * 64 + (size_t)c * 64 * K, dA + buf * 16384 + c * 4096);
  };
  auto stB = [&](int tile, int c, int buf) {
    gld16(bS + (size_t)tile * 64 + (size_t)c * 64 * K, dB + buf * 16384 + c * 4096);
  };

#pragma unroll
  for (int c = 0; c < 4; ++c) stA(0, c, 0);
#pragma unroll
  for (int c = 0; c < 4; ++c) stB(0, c, 0);
  if (NT > 1) {
    stA(1, 0, 1); stA(1, 2, 1);
    stB(1, 0, 1); stB(1, 1, 1); stB(1, 2, 1); stB(1, 3, 1);
  }

  for (int t = 0; t < NT; ++t) {
    const int cur = t & 1;
    const u16* At = lds + cur * 16384;
    const u16* Bt = lds + 32768 + cur * 16384;

    if (t + 1 < NT) asm volatile("s_waitcnt vmcnt(6)" ::: "memory");
    else            asm volatile("s_waitcnt vmcnt(0)" ::: "memory");
    __builtin_amdgcn_s_barrier();

    bfrag a[4][2], b[2][2][2];

#pragma unroll
    for (int m = 0; m < 4; ++m) {
      const u16* p = At + (wm * 128 + m * 16 + fr) * 64;
      a[m][0] = *(const bfrag*)(p + g0);
      a[m][1] = *(const bfrag*)(p + g1);
    }
#pragma unroll
    for (int n = 0; n < 2; ++n) {
      const u16* p = Bt + (wn * 64 + n * 16 + fr) * 64;
      b[0][n][0] = *(const bfrag*)(p + g0);
      b[0][n][1] = *(const bfrag*)(p + g1);
    }
    if (t + 1 < NT) { stA(t + 1, 1, cur ^ 1); stA(t + 1, 3, cur ^ 1); }
    __builtin_amdgcn_s_barrier();
    asm volatile("s_waitcnt lgkmcnt(0)" ::: "memory");
    __builtin_amdgcn_sched_barrier(0);
    __builtin_amdgcn_s_setprio(1);
#pragma unroll
    for (int n = 0; n < 2; ++n)
#pragma unroll
      for (int m = 0; m < 4; ++m) {
        acc[m][n] = __builtin_amdgcn_mfma_f32_16x16x32_bf16(a[m][0], b[0][n][0], acc[m][n], 0, 0, 0);
        acc[m][n] = __builtin_amdgcn_mfma_f32_16x16x32_bf16(a[m][1], b[0][n][1], acc[m][n], 0, 0, 0);
      }
    __builtin_amdgcn_s_setprio(0);
    __builtin_amdgcn_s_barrier();

#pragma unroll
    for (int n = 0; n < 2; ++n) {
      const u16* p = Bt + (wn * 64 + 32 + n * 16 + fr) * 64;
      b[1][n][0] = *(const bfrag*)(p + g0);
      b[1][n][1] = *(const bfrag*)(p + g1);
    }
    if (t + 2 < NT) { stA(t + 2, 0, cur); stA(t + 2, 2, cur); }
    __builtin_amdgcn_s_barrier();
    asm volatile("s_waitcnt lgkmcnt(0)" ::: "memory");
    __builtin_amdgcn_sched_barrier(0);
    __builtin_amdgcn_s_setprio(1);
#pragma unroll
    for (int n = 0; n < 2; ++n)
#pragma unroll
      for (int m = 0; m < 4; ++m) {
        acc[m][2 + n] = __builtin_amdgcn_mfma_f32_16x16x32_bf16(a[m][0], b[1][n][0], acc[m][2 + n], 0, 0, 0);
        acc[m][2 + n] = __builtin_amdgcn_mfma_f32_16x16x32_bf16(a[m][1], b[1][n][1], acc[m][2 + n], 0, 0, 0);
      }
    __builtin_amdgcn_s_setprio(0);
    __builtin_amdgcn_s_barrier();

#pragma unroll
    for (int m = 0; m < 4; ++m) {
      const u16* p = At + (wm * 128 + 64 + m * 16 + fr) * 64;
      a[m][0] = *(const bfrag*)(p + g0);
      a[m][1] = *(const bfrag*)(p + g1);
    }
    if (t + 2 < NT) { stB(t + 2, 0, cur); stB(t + 2, 1, cur); }
    __builtin_amdgcn_s_barrier();
    asm volatile("s_waitcnt lgkmcnt(0)" ::: "memory");
    __builtin_amdgcn_sched_barrier(0);
    __builtin_amdgcn_s_setprio(1);
#pragma unroll
    for (int n = 0; n < 2; ++n)
#pragma unroll
      for (int m = 0; m < 4; ++m) {
        acc[4 + m][n] = __builtin_amdgcn_mfma_f32_16x16x32_bf16(a[m][0], b[0][n][0], acc[4 + m][n], 0, 0, 0);
        acc[4 + m][n] = __builtin_amdgcn_mfma_f32_16x16x32_bf16(a[m][1], b[0][n][1], acc[4 + m][n], 0, 0, 0);
      }
    __builtin_amdgcn_s_setprio(0);
    __builtin_amdgcn_s_barrier();

    if (t + 2 < NT) { stB(t + 2, 2, cur); stB(t + 2, 3, cur); }
    __builtin_amdgcn_s_setprio(1);
#pragma unroll
    for (int n = 0; n < 2; ++n)
#pragma unroll
      for (int m = 0; m < 4; ++m) {
        acc[4 + m][2 + n] = __builtin_amdgcn_mfma_f32_16x16x32_bf16(a[m][0], b[1][n][0], acc[4 + m][2 + n], 0, 0, 0);
        acc[4 + m][2 + n] = __builtin_amdgcn_mfma_f32_16x16x32_bf16(a[m][1], b[1][n][1], acc[4 + m][2 + n], 0, 0, 0);
      }
    __builtin_amdgcn_s_setprio(0);
    __builtin_amdgcn_s_barrier();
  }

#pragma unroll
  for (int mg = 0; mg < 8; ++mg) {
    const int r0 = brow + wm * 128 + mg * 16 + fq * 4;
#pragma unroll
    for (int n = 0; n < 4; ++n) {
      const int c = bcol + wn * 64 + n * 16 + fr;
      f32x4 vv = acc[mg][n];
      float bb = bias[c];
      if constexpr (OUT == 0) {
        u16* C = (u16*)outp;
#pragma unroll
        for (int j = 0; j < 4; ++j) C[(size_t)(r0 + j) * ldc + c] = f2bf(vv[j] + bb);
      } else {
        const int bz2 = r0 >> 11, mm = r0 & 2047;
        us4 o;
#pragma unroll
        for (int j = 0; j < 4; ++j) o[j] = f2bf(vv[j] + bb);
        *(us4*)((u16*)outp + ((size_t)bz2 * 1024 + c) * 2048 + mm) = o;
      }
    }
  }
}

// ---------------------------------------------------------------------------
// Kernel 3 (scores/PV): 128x128-tile BT GEMM, BK=64, 512 threads (8 waves,
//   2M x 4N). 64 KiB LDS double-buffered, 2 blocks/CU.
//   SUPERTILE XCD MAPPING: id = xcd(3b) | j(4b) | st. The 16 blocks a given
//   XCD holds co-resident (ids c, c+8, ..., c+120) form a 4x4 block supertile
//   of one batch -> per-XCD working set ~2-4 MB (L2-fit) instead of ~48 MB.
// OUT==1 (scores, grid 16x16x8): early-exit masked cols.
// OUT==3 (PV, grid 8x16x8): K truncated at ceil64(len).
// ---------------------------------------------------------------------------
template <int OUT>
__global__ __launch_bounds__(512, 4) void gemm128d(const u16* __restrict__ gA,
                                                   const u16* __restrict__ gB,
                                                   void* __restrict__ outp,
                                                   int K, int ldc,
                                                   size_t aStride, size_t bStride,
                                                   size_t cStride,
                                                   const int* __restrict__ seq) {
  __shared__ u16 lds[32768];   // A: 2 bufs of 8192 u16; B: +16384
  const int tid = threadIdx.x;

  const int id = blockIdx.x + gridDim.x * (blockIdx.y + gridDim.y * blockIdx.z);
  int bx, by, bz;
  {
    const int j = (id >> 3) & 15;          // position within supertile (4x4)
    if constexpr (OUT == 1) {              // 2048 blocks: st = id>>7 (4b)
      const int S = (id & 7) + ((id >> 7) << 3);   // supertile id in [0,128)
      bz = S >> 4;
      const int s4 = S & 15;
      by = ((s4 >> 2) << 2) + (j >> 2);
      bx = ((s4 & 3) << 2) + (j & 3);
    } else {                               // 1024 blocks: st = id>>7 (3b)
      const int S = (id & 7) + ((id >> 7) << 3);   // supertile id in [0,64)
      bz = S >> 3;
      const int s4 = S & 7;
      by = ((s4 >> 1) << 2) + (j >> 2);
      bx = ((s4 & 1) << 2) + (j & 3);
    }
  }

  const u16* A = gA + (size_t)bz * aStride;
  const u16* B = gB + (size_t)bz * bStride;
  const int brow = by * 128, bcol = bx * 128;

  const int NT = K >> 6;
  int t1 = NT;
  if constexpr (OUT == 1) {
    if (bcol >= seq[bz]) return;
  }
  if constexpr (OUT == 3) {
    const int nt2 = (seq[bz] + 63) >> 6;
    t1 = nt2 < NT ? nt2 : NT;
  }

  const int wv = tid >> 6, l = tid & 63;
  const int wm = wv >> 2, wn = wv & 3;          // 2M x 4N
  const int fr = l & 15, fq = l >> 4;
  const int g0 = (fq ^ (fr & 7)) * 8;
  const int g1 = ((4 + fq) ^ (fr & 7)) * 8;

  const int srow = tid >> 3;                    // 0..63
  const int sg = (tid & 7) ^ (srow & 7);
  const u16* aS = A + (size_t)(brow + srow) * K + sg * 8;
  const u16* bS = B + (size_t)(bcol + srow) * K + sg * 8;
  u16* const dA = lds + wv * 512;
  u16* const dB = lds + 16384 + wv * 512;

  f32x4 acc[4][2] = {};

  auto stage = [&](int tile, int buf) {
#pragma unroll
    for (int c = 0; c < 2; ++c)
      gld16(aS + (size_t)tile * 64 + (size_t)c * 64 * K, dA + buf * 8192 + c * 4096);
#pragma unroll
    for (int c = 0; c < 2; ++c)
      gld16(bS + (size_t)tile * 64 + (size_t)c * 64 * K, dB + buf * 8192 + c * 4096);
  };

  // prologue
  stage(0, 0);
  asm volatile("s_waitcnt vmcnt(0)" ::: "memory");
  __builtin_amdgcn_s_barrier();

  for (int t = 0; t < t1; ++t) {
    const int cur = t & 1;
    const u16* At = lds + cur * 8192;
    const u16* Bt = lds + 16384 + cur * 8192;

    if (t + 1 < t1) stage(t + 1, cur ^ 1);   // issue early; lands during MFMA

    bfrag a[4][2], b[2][2];
#pragma unroll
    for (int m = 0; m < 4; ++m) {
      const u16* p = At + (wm * 64 + m * 16 + fr) * 64;
      a[m][0] = *(const bfrag*)(p + g0);
      a[m][1] = *(const bfrag*)(p + g1);
    }
#pragma unroll
    for (int n = 0; n < 2; ++n) {
      const u16* p = Bt + (wn * 32 + n * 16 + fr) * 64;
      b[n][0] = *(const bfrag*)(p + g0);
      b[n][1] = *(const bfrag*)(p + g1);
    }
    asm volatile("s_waitcnt lgkmcnt(0)" ::: "memory");
    __builtin_amdgcn_sched_barrier(0);
    __builtin_amdgcn_s_setprio(1);
#pragma unroll
    for (int m = 0; m < 4; ++m)
#pragma unroll
      for (int n = 0; n < 2; ++n) {
        acc[m][n] = __builtin_amdgcn_mfma_f32_16x16x32_bf16(a[m][0], b[n][0], acc[m][n], 0, 0, 0);
        acc[m][n] = __builtin_amdgcn_mfma_f32_16x16x32_bf16(a[m][1], b[n][1], acc[m][n], 0, 0, 0);
      }
    __builtin_amdgcn_s_setprio(0);
    if (t + 1 < t1) asm volatile("s_waitcnt vmcnt(0)" ::: "memory");
    __builtin_amdgcn_s_barrier();
  }

  // epilogue
#pragma unroll
  for (int m = 0; m < 4; ++m) {
    const int r0 = brow + wm * 64 + m * 16 + fq * 4;
#pragma unroll
    for (int n = 0; n < 2; ++n) {
      const int c = bcol + wn * 32 + n * 16 + fr;
      f32x4 vv = acc[m][n];
      if constexpr (OUT == 1) {
        u16* C = (u16*)outp + (size_t)bz * cStride;
#pragma unroll
        for (int j = 0; j < 4; ++j) C[(size_t)(r0 + j) * ldc + c] = f2bf(vv[j] * 0.03125f);
      } else {
        float* C = (float*)outp + (size_t)bz * cStride;
#pragma unroll
        for (int j = 0; j < 4; ++j) C[(size_t)(r0 + j) * ldc + c] = vv[j];
      }
    }
  }
}

// ---------------------------------------------------------------------------
// Kernel 4: masked softmax over m, in place on probs (bf16). One block per row.
// ---------------------------------------------------------------------------
__global__ __launch_bounds__(256) void softmax_mask(u16* __restrict__ probs,
                                                    const int* __restrict__ seq) {
  const int bid = blockIdx.x;
  const int b = bid >> 11, n = bid & 2047;
  const int len = seq[b];
  const int len64 = (len + 63) & ~63;
  u16* row = probs + ((size_t)b * 2048 + n) * 2048;
  const int t = threadIdx.x;
  const int w = t >> 6, l = t & 63;

  us8 sv = {};
  if (t * 8 < len) sv = *(const us8*)(row + t * 8);
  float vals[8];
  float vmax = -1e30f;
#pragma unroll
  for (int e = 0; e < 8; ++e) {
    int m = t * 8 + e;
    float x = bf2f(sv[e]);
    vals[e] = (m < len) ? x : -1e30f;
    vmax = fmaxf(vmax, vals[e]);
  }
#pragma unroll
  for (int o = 32; o > 0; o >>= 1) vmax = fmaxf(vmax, __shfl_xor(vmax, o, 64));
  __shared__ float sm[4], ss[4];
  if (l == 0) sm[w] = vmax;
  __syncthreads();
  vmax = fmaxf(fmaxf(sm[0], sm[1]), fmaxf(sm[2], sm[3]));

  float ev[8];
  float sum = 0.f;
#pragma unroll
  for (int e = 0; e < 8; ++e) {
    int m = t * 8 + e;
    float p = (m < len) ? __expf(vals[e] - vmax) : 0.f;
    ev[e] = p;
    sum += p;
  }
#pragma unroll
  for (int o = 32; o > 0; o >>= 1) sum += __shfl_xor(sum, o, 64);
  if (l == 0) ss[w] = sum;
  __syncthreads();
  sum = ss[0] + ss[1] + ss[2] + ss[3];
  float inv = 1.f / sum;
  if (t * 8 < len64) {
    us8 ov;
#pragma unroll
    for (int e = 0; e < 8; ++e) ov[e] = f2bf(ev[e] * inv);
    *(us8*)(row + t * 8) = ov;
  }
}

// ---------------------------------------------------------------------------
extern "C" void kernel_launch(void* const* d_in, const int* in_sizes, int n_in,
                              void* d_out, int out_size, void* d_ws, size_t ws_size,
                              hipStream_t stream) {
  const float* q   = (const float*)d_in[0];
  const float* k   = (const float*)d_in[1];
  const float* v   = (const float*)d_in[2];
  const int*   seq = (const int*)d_in[3];
  const float* Wq  = (const float*)d_in[4];
  const float* bq  = (const float*)d_in[5];
  const float* Wk  = (const float*)d_in[6];
  const float* bk  = (const float*)d_in[7];
  const float* Wv  = (const float*)d_in[8];
  const float* bv  = (const float*)d_in[9];
  float* out = (float*)d_out;

  // workspace layout (u16 elements) — ~166 MB:
  //   wt: 3 x 1M | lq/lk/lvt: 3 x 16M | probs: 33.5M (cvt buffer aliased in)
  u16* ws = (u16*)d_ws;
  u16* wtq = ws;
  u16* wtk = wtq + (size_t)1024 * 1024;
  u16* wtv = wtk + (size_t)1024 * 1024;
  u16* lq  = wtv + (size_t)1024 * 1024;
  u16* lk  = lq + (size_t)16384 * 1024;
  u16* lvt = lk + (size_t)16384 * 1024;
  u16* probs = lvt + (size_t)16384 * 1024;
  u16* cbuf = probs;          // 16M u16 convert buffer (dead before scores)

  const size_t S21 = (size_t)2048 * 1024;   // per-batch stride, 2048x1024
  const size_t S22 = (size_t)2048 * 2048;   // per-batch stride, 2048x2048

  transpose_w<<<dim3(16, 16, 3), 256, 0, stream>>>(Wq, Wk, Wv, wtq, wtk, wtv);

  // Q projection
  cvt_bf16<<<dim3(2048), 256, 0, stream>>>(q, cbuf, 2097152);
  gemm256<0><<<dim3(4, 64, 1), 512, 0, stream>>>(cbuf, wtq, bq, lq, 1024, 1024);
  // K projection
  cvt_bf16<<<dim3(2048), 256, 0, stream>>>(k, cbuf, 2097152);
  gemm256<0><<<dim3(4, 64, 1), 512, 0, stream>>>(cbuf, wtk, bk, lk, 1024, 1024);
  // V projection -> transposed lvt[b][o][m]
  cvt_bf16<<<dim3(2048), 256, 0, stream>>>(v, cbuf, 2097152);
  gemm256<2><<<dim3(4, 64, 1), 512, 0, stream>>>(cbuf, wtv, bv, lvt, 1024, 1024);

  // scores = lq @ lk^T / 32  (per batch, masked tiles skipped, supertile map)
  gemm128d<1><<<dim3(16, 16, 8), 512, 0, stream>>>(lq, lk, probs, 1024, 2048,
                                                   S21, S21, S22, seq);
  // masked softmax in place
  softmax_mask<<<dim3(16384), 256, 0, stream>>>(probs, seq);
  // out = probs @ lv  (per batch, lvt B^T layout, K truncated, supertile map)
  gemm128d<3><<<dim3(8, 16, 8), 512, 0, stream>>>(probs, lvt, out, 2048, 1024,
                                                  S22, S21, S21, seq);
}